// Round 12
// baseline (741.675 us; speedup 1.0000x reference)
//
#include <hip/hip_runtime.h>
#include <hip/hip_bf16.h>
#include <cmath>

#define N_NODES 100000
#define N_EDGES 1600000
#define IN_F 48
#define HID_F 16
#define OUT_F 60

#define BKT 256                                  // nodes per bucket
#define NBKT ((N_NODES + BKT - 1) / BKT)         // 391
#define EPB 8192                                 // edges per partition block
#define NB_P ((N_EDGES + EPB - 1) / EPB)         // 196
#define EPB_H 2048                               // edges per hist block
#define NB_H ((N_EDGES + EPB_H - 1) / EPB_H)     // 782
#define DBINS 64                                 // degree bins for perm sort

typedef __hip_bfloat16 bf16;
typedef float f32x4 __attribute__((ext_vector_type(4)));
typedef unsigned int u32;

__device__ __forceinline__ float bf2f(u32 u)
{
    return __uint_as_float(u << 16);
}
__device__ __forceinline__ u32 pack_bf2(float lo, float hi)
{
    u32 l = __bfloat16_as_ushort(__float2bfloat16(lo));
    u32 h = __bfloat16_as_ushort(__float2bfloat16(hi));
    return l | (h << 16);
}

// ---------------- Build: two-level counting sort -> per-node CSR --------------
__global__ __launch_bounds__(256) void k_bhist(
    const int* __restrict__ dst, int* __restrict__ bcnt)
{
    __shared__ int h[NBKT];
    for (int i = threadIdx.x; i < NBKT; i += 256) h[i] = 0;
    __syncthreads();
    int base = blockIdx.x * EPB_H;
    #pragma unroll
    for (int i = 0; i < EPB_H / 256; ++i) {
        int e = base + i * 256 + threadIdx.x;
        if (e < N_EDGES) atomicAdd(&h[dst[e] >> 8], 1);
    }
    __syncthreads();
    for (int i = threadIdx.x; i < NBKT; i += 256)
        if (h[i]) atomicAdd(&bcnt[i], h[i]);
}

__global__ __launch_bounds__(1024) void k_bscan(
    const int* __restrict__ bcnt, int* __restrict__ base, int* __restrict__ cursor)
{
    __shared__ int tmp[1024];
    int v = (threadIdx.x < NBKT) ? bcnt[threadIdx.x] : 0;
    tmp[threadIdx.x] = v;
    __syncthreads();
    #pragma unroll
    for (int ofs = 1; ofs < 1024; ofs <<= 1) {
        int a = (threadIdx.x >= ofs) ? tmp[threadIdx.x - ofs] : 0;
        __syncthreads();
        tmp[threadIdx.x] += a;
        __syncthreads();
    }
    if (threadIdx.x < NBKT) {
        int ex = tmp[threadIdx.x] - v;
        base[threadIdx.x] = ex;
        cursor[threadIdx.x] = ex;
    }
    if (threadIdx.x == 0) base[NBKT] = N_EDGES;
}

// Partition edges into dst-buckets; packed word = (src << 8) | (dst & 255).
__global__ __launch_bounds__(1024) void k_partition(
    const int* __restrict__ src, const int* __restrict__ dst,
    int* __restrict__ cursor, u32* __restrict__ pk)
{
    __shared__ int cnt[NBKT];
    __shared__ int bb[NBKT];
    for (int i = threadIdx.x; i < NBKT; i += 1024) cnt[i] = 0;
    __syncthreads();
    int e0 = blockIdx.x * EPB;
    int dloc[EPB / 1024];
    #pragma unroll
    for (int i = 0; i < EPB / 1024; ++i) {
        int e = e0 + i * 1024 + threadIdx.x;
        dloc[i] = (e < N_EDGES) ? dst[e] : -1;
        if (dloc[i] >= 0) atomicAdd(&cnt[dloc[i] >> 8], 1);
    }
    __syncthreads();
    for (int i = threadIdx.x; i < NBKT; i += 1024) {
        int c = cnt[i];
        bb[i] = c ? atomicAdd(&cursor[i], c) : 0;
        cnt[i] = 0;
    }
    __syncthreads();
    #pragma unroll
    for (int i = 0; i < EPB / 1024; ++i) {
        int e = e0 + i * 1024 + threadIdx.x;
        int d = dloc[i];
        if (d >= 0) {
            int b = d >> 8;
            int r = atomicAdd(&cnt[b], 1);
            pk[bb[b] + r] = ((u32)src[e] << 8) | (u32)(d & 255);
        }
    }
}

// One block per 256-node bucket (16 waves): per-node CSR in a 16KB hot window.
// Also feeds the degree histogram for the perm counting sort.
__global__ __launch_bounds__(1024) void k_bucket_csr(
    const int* __restrict__ base, const u32* __restrict__ pk,
    int* __restrict__ off_end, int* __restrict__ csr, int* __restrict__ dcnt)
{
    __shared__ int hist[BKT];
    __shared__ int tmp[BKT];
    __shared__ int cur[BKT];
    int b = blockIdx.x;
    int e0 = base[b], e1 = base[b + 1];
    if (threadIdx.x < BKT) hist[threadIdx.x] = 0;
    __syncthreads();
    for (int e = e0 + threadIdx.x; e < e1; e += 1024)
        atomicAdd(&hist[pk[e] & 255u], 1);
    __syncthreads();
    int v = 0;
    if (threadIdx.x < BKT) { v = hist[threadIdx.x]; tmp[threadIdx.x] = v; }
    __syncthreads();
    #pragma unroll
    for (int ofs = 1; ofs < BKT; ofs <<= 1) {
        int a = (threadIdx.x < BKT && threadIdx.x >= ofs) ? tmp[threadIdx.x - ofs] : 0;
        __syncthreads();
        if (threadIdx.x < BKT) tmp[threadIdx.x] += a;
        __syncthreads();
    }
    if (threadIdx.x < BKT) {
        int incl = tmp[threadIdx.x];
        cur[threadIdx.x] = e0 + incl - v;
        int n = b * BKT + threadIdx.x;
        if (n < N_NODES) {
            off_end[n] = e0 + incl;
            atomicAdd(&dcnt[v < DBINS - 1 ? v : DBINS - 1], 1);  // deg histogram
        }
    }
    __syncthreads();
    for (int e = e0 + threadIdx.x; e < e1; e += 1024) {
        u32 p = pk[e];
        int pos = atomicAdd(&cur[p & 255u], 1);
        csr[pos] = (int)(p >> 8);
    }
}

// Exclusive scan of the 64 degree-bin counts -> dcur (fill cursors).
__global__ __launch_bounds__(64) void k_degscan(
    const int* __restrict__ dcnt, int* __restrict__ dcur)
{
    __shared__ int tmp[DBINS];
    int v = dcnt[threadIdx.x];
    tmp[threadIdx.x] = v;
    __syncthreads();
    #pragma unroll
    for (int ofs = 1; ofs < DBINS; ofs <<= 1) {
        int a = (threadIdx.x >= ofs) ? tmp[threadIdx.x - ofs] : 0;
        __syncthreads();
        tmp[threadIdx.x] += a;
        __syncthreads();
    }
    dcur[threadIdx.x] = tmp[threadIdx.x] - v;
}

// Fill perm: nodes in ascending-degree order (order within a bin arbitrary —
// output is order-independent since each node's math is self-contained).
__global__ __launch_bounds__(256) void k_permfill(
    const int* __restrict__ off_end, int* __restrict__ dcur, int* __restrict__ perm)
{
    int n = blockIdx.x * 256 + threadIdx.x;
    if (n >= N_NODES) return;
    int e0 = (n == 0) ? 0 : off_end[n - 1];
    int d = off_end[n] - e0;
    int bin = d < DBINS - 1 ? d : DBINS - 1;
    int pos = atomicAdd(&dcur[bin], 1);
    perm[pos] = n;
}

// Gather body: 8 lanes per node; lane = feature PAIR (u32 = 2 bf16).
__device__ __forceinline__ float2 gather2(
    const int* __restrict__ off_end, const int* __restrict__ csr_src,
    const u32* __restrict__ Yu, int n, int lane)
{
    int e0 = (n == 0) ? 0 : off_end[n - 1];
    int e1 = off_end[n];
    float x0 = 0.f, y0 = 0.f, x1 = 0.f, y1 = 0.f;
    float x2 = 0.f, y2 = 0.f, x3 = 0.f, y3 = 0.f;
    int e = e0;
    for (; e + 3 < e1; e += 4) {
        int s0 = csr_src[e];
        int s1 = csr_src[e + 1];
        int s2 = csr_src[e + 2];
        int s3 = csr_src[e + 3];
        u32 u0 = Yu[(size_t)s0 * 8 + lane];
        u32 u1 = Yu[(size_t)s1 * 8 + lane];
        u32 u2 = Yu[(size_t)s2 * 8 + lane];
        u32 u3 = Yu[(size_t)s3 * 8 + lane];
        x0 += bf2f(u0 & 0xffffu); y0 += bf2f(u0 >> 16);
        x1 += bf2f(u1 & 0xffffu); y1 += bf2f(u1 >> 16);
        x2 += bf2f(u2 & 0xffffu); y2 += bf2f(u2 >> 16);
        x3 += bf2f(u3 & 0xffffu); y3 += bf2f(u3 >> 16);
    }
    for (; e < e1; ++e) {
        u32 u = Yu[(size_t)csr_src[e] * 8 + lane];
        x0 += bf2f(u & 0xffffu); y0 += bf2f(u >> 16);
    }
    return make_float2((x0 + x1) + (x2 + x3), (y0 + y1) + (y2 + y3));
}

// ------- Layer-1: Ya = bf16(x@W1_rel), R = x@W1_root + b1; block 0 zeros bins -
__global__ __launch_bounds__(256) void k1_lin48(
    const float* __restrict__ x, const float* __restrict__ Wrel,
    const float* __restrict__ b, const float* __restrict__ Wroot,
    bf16* __restrict__ Ya, float* __restrict__ R,
    int* __restrict__ bcnt, int* __restrict__ dcnt)
{
    if (blockIdx.x == 0) {
        for (int i = threadIdx.x; i < NBKT; i += 256) bcnt[i] = 0;
        if (threadIdx.x < DBINS) dcnt[threadIdx.x] = 0;
    }

    __shared__ float sWrel[IN_F * HID_F];
    __shared__ float sWroot[IN_F * HID_F];
    __shared__ float sb[HID_F];
    for (int i = threadIdx.x; i < IN_F * HID_F; i += 256) {
        sWrel[i]  = Wrel[i];
        sWroot[i] = Wroot[i];
    }
    if (threadIdx.x < HID_F) sb[threadIdx.x] = b[threadIdx.x];
    __syncthreads();

    int n = blockIdx.x * 256 + threadIdx.x;
    if (n >= N_NODES) return;

    float xv[IN_F];
    const f32x4* xr = reinterpret_cast<const f32x4*>(x + (size_t)n * IN_F);
    #pragma unroll
    for (int i = 0; i < IN_F / 4; ++i) {
        f32x4 t = __builtin_nontemporal_load(xr + i);   // x read exactly once
        xv[4*i+0] = t.x; xv[4*i+1] = t.y; xv[4*i+2] = t.z; xv[4*i+3] = t.w;
    }

    float accR[HID_F], accT[HID_F];
    #pragma unroll
    for (int f = 0; f < HID_F; ++f) { accR[f] = 0.0f; accT[f] = sb[f]; }

    #pragma unroll 6
    for (int k = 0; k < IN_F; ++k) {
        float xk = xv[k];
        #pragma unroll
        for (int f = 0; f < HID_F; ++f) {
            accR[f] = fmaf(xk, sWrel[k*HID_F + f], accR[f]);
            accT[f] = fmaf(xk, sWroot[k*HID_F + f], accT[f]);
        }
    }

    union { bf16 h[HID_F]; uint4 q[2]; } yo;
    #pragma unroll
    for (int f = 0; f < HID_F; ++f) yo.h[f] = __float2bfloat16(accR[f]);
    uint4* yq = reinterpret_cast<uint4*>(Ya + (size_t)n * HID_F);
    yq[0] = yo.q[0]; yq[1] = yo.q[1];

    float4* rr = reinterpret_cast<float4*>(R + (size_t)n * HID_F);
    #pragma unroll
    for (int q = 0; q < HID_F / 4; ++q)
        rr[q] = make_float4(accT[4*q], accT[4*q+1], accT[4*q+2], accT[4*q+3]);
}

// -------- kA: gather(Ya) + h=tanh(R+agg); Yb=bf16(h@Wrel); R=h@Wroot+b --------
// 8 lanes/node via perm (degree-sorted schedule: uniform wave workloads).
__global__ __launch_bounds__(256) void kA_gather_lin16(
    const int* __restrict__ off_end, const int* __restrict__ csr_src,
    const int* __restrict__ perm,
    const bf16* __restrict__ Ya, float* __restrict__ R,
    const float* __restrict__ Wrel, const float* __restrict__ bb,
    const float* __restrict__ Wroot, bf16* __restrict__ Yb)
{
    __shared__ float2 sWrel2[HID_F * 8];     // [k][pair l] = (W[k][2l], W[k][2l+1])
    __shared__ float2 sWroot2[HID_F * 8];
    __shared__ float2 sb2[8];
    if (threadIdx.x < HID_F * 8) {
        sWrel2[threadIdx.x]  = reinterpret_cast<const float2*>(Wrel)[threadIdx.x];
        sWroot2[threadIdx.x] = reinterpret_cast<const float2*>(Wroot)[threadIdx.x];
    }
    if (threadIdx.x < 8) sb2[threadIdx.x] = reinterpret_cast<const float2*>(bb)[threadIdx.x];
    __syncthreads();

    int t = blockIdx.x * 256 + threadIdx.x;
    int g = t >> 3;
    int lane = t & 7;
    if (g >= N_NODES) return;
    int n = perm[g];

    float2 agg = gather2(off_end, csr_src, (const u32*)Ya, n, lane);
    float2 r = reinterpret_cast<const float2*>(R)[(size_t)n * 8 + lane];
    float hx_own = tanhf(r.x + agg.x);
    float hy_own = tanhf(r.y + agg.y);

    int base = threadIdx.x & 56;   // 8-lane group base within the wave
    float2 accR = make_float2(0.f, 0.f);
    float2 accT = sb2[lane];
    #pragma unroll
    for (int kk = 0; kk < 8; ++kk) {
        float hx = __shfl(hx_own, base | kk);   // feature k0 = 2*kk
        float hy = __shfl(hy_own, base | kk);   // feature k1 = 2*kk+1
        float2 w0r = sWrel2[(2*kk)   * 8 + lane];
        float2 w1r = sWrel2[(2*kk+1) * 8 + lane];
        float2 w0t = sWroot2[(2*kk)   * 8 + lane];
        float2 w1t = sWroot2[(2*kk+1) * 8 + lane];
        accR.x = fmaf(hx, w0r.x, accR.x); accR.y = fmaf(hx, w0r.y, accR.y);
        accR.x = fmaf(hy, w1r.x, accR.x); accR.y = fmaf(hy, w1r.y, accR.y);
        accT.x = fmaf(hx, w0t.x, accT.x); accT.y = fmaf(hx, w0t.y, accT.y);
        accT.x = fmaf(hy, w1t.x, accT.x); accT.y = fmaf(hy, w1t.y, accT.y);
    }

    ((u32*)Yb)[(size_t)n * 8 + lane] = pack_bf2(accR.x, accR.y);
    reinterpret_cast<float2*>(R)[(size_t)n * 8 + lane] = accT;
}

// -------- kB: h2 = tanh(R + gather(Yb)); Ya = bf16(h2) ------------------------
__global__ __launch_bounds__(256) void kB_gather_tanh(
    const int* __restrict__ off_end, const int* __restrict__ csr_src,
    const int* __restrict__ perm,
    const bf16* __restrict__ Yb, const float* __restrict__ R,
    bf16* __restrict__ Ya)
{
    int t = blockIdx.x * 256 + threadIdx.x;
    int g = t >> 3;
    int lane = t & 7;
    if (g >= N_NODES) return;
    int n = perm[g];

    float2 agg = gather2(off_end, csr_src, (const u32*)Yb, n, lane);
    float2 r = reinterpret_cast<const float2*>(R)[(size_t)n * 8 + lane];
    ((u32*)Ya)[(size_t)n * 8 + lane] =
        pack_bf2(tanhf(r.x + agg.x), tanhf(r.y + agg.y));
}

// -------- kC: out = gather(Ya)@W2_rel + b2 + Ya[n]@W2_root --------------------
__global__ __launch_bounds__(256) void kC_gather_out(
    const int* __restrict__ off_end, const int* __restrict__ csr_src,
    const int* __restrict__ perm,
    const bf16* __restrict__ Ya,
    const float* __restrict__ Wrel, const float* __restrict__ b2,
    const float* __restrict__ Wroot, float* __restrict__ out)
{
    __shared__ float sWrel[HID_F * OUT_F];
    __shared__ float sWroot[HID_F * OUT_F];
    __shared__ float sb[OUT_F];
    for (int i = threadIdx.x; i < HID_F * OUT_F; i += 256) {
        sWrel[i]  = Wrel[i];
        sWroot[i] = Wroot[i];
    }
    if (threadIdx.x < OUT_F) sb[threadIdx.x] = b2[threadIdx.x];
    __syncthreads();

    int t = blockIdx.x * 256 + threadIdx.x;
    int g = t >> 3;
    int lane = t & 7;
    if (g >= N_NODES) return;
    int n = perm[g];

    float2 agg = gather2(off_end, csr_src, (const u32*)Ya, n, lane);
    u32 hown = ((const u32*)Ya)[(size_t)n * 8 + lane];
    float hx_own = bf2f(hown & 0xffffu);
    float hy_own = bf2f(hown >> 16);

    int base = threadIdx.x & 56;
    float acc[8];
    #pragma unroll
    for (int q = 0; q < 8; ++q) {
        int j = q * 8 + lane;
        acc[q] = (j < OUT_F) ? sb[j] : 0.f;
    }
    #pragma unroll
    for (int kk = 0; kk < 8; ++kk) {
        float ax = __shfl(agg.x, base | kk);   // agg feature 2*kk
        float ay = __shfl(agg.y, base | kk);   // agg feature 2*kk+1
        float hx = __shfl(hx_own, base | kk);
        float hy = __shfl(hy_own, base | kk);
        const float* wr0 = sWrel  + (2*kk)   * OUT_F;
        const float* wr1 = sWrel  + (2*kk+1) * OUT_F;
        const float* wt0 = sWroot + (2*kk)   * OUT_F;
        const float* wt1 = sWroot + (2*kk+1) * OUT_F;
        #pragma unroll
        for (int q = 0; q < 8; ++q) {
            int j = q * 8 + lane;
            if (j < OUT_F) {
                acc[q] = fmaf(ax, wr0[j], acc[q]);
                acc[q] = fmaf(ay, wr1[j], acc[q]);
                acc[q] = fmaf(hx, wt0[j], acc[q]);
                acc[q] = fmaf(hy, wt1[j], acc[q]);
            }
        }
    }
    // nt store: out is a pure write-once stream; keep Ya resident in L2.
    float* orow = out + (size_t)n * OUT_F;
    #pragma unroll
    for (int q = 0; q < 8; ++q) {
        int j = q * 8 + lane;
        if (j < OUT_F) __builtin_nontemporal_store(acc[q], orow + j);
    }
}

extern "C" void kernel_launch(void* const* d_in, const int* in_sizes, int n_in,
                              void* d_out, int out_size, void* d_ws, size_t ws_size,
                              hipStream_t stream)
{
    const float* x        = (const float*)d_in[0];
    const int*   ei       = (const int*)d_in[1];
    const float* W1_rel   = (const float*)d_in[2];
    const float* b1       = (const float*)d_in[3];
    const float* W1_root  = (const float*)d_in[4];
    const float* W1b_rel  = (const float*)d_in[5];
    const float* b1b      = (const float*)d_in[6];
    const float* W1b_root = (const float*)d_in[7];
    const float* W2_rel   = (const float*)d_in[8];
    const float* b2       = (const float*)d_in[9];
    const float* W2_root  = (const float*)d_in[10];
    float* out = (float*)d_out;

    const int* src = ei;            // edge_index[0]
    const int* dst = ei + N_EDGES;  // edge_index[1]

    // Workspace (~20.0 MB). pk aliases d_out (consumed in build, before kC).
    bf16* Ya     = (bf16*)d_ws;                           // [N,16] bf16
    bf16* Yb     = Ya + (size_t)N_NODES * HID_F;          // [N,16] bf16
    float* R     = (float*)(Yb + (size_t)N_NODES * HID_F);// [N,16] f32
    int* csr     = (int*)(R + (size_t)N_NODES * HID_F);   // [E]
    int* off_end = csr + N_EDGES;                         // [N]
    int* perm    = off_end + N_NODES;                     // [N]
    int* bcnt    = perm + N_NODES;                        // [NBKT]
    int* base    = bcnt + NBKT;                           // [NBKT+1]
    int* cursor  = base + NBKT + 1;                       // [NBKT]
    int* dcnt    = cursor + NBKT;                         // [DBINS]
    int* dcur    = dcnt + DBINS;                          // [DBINS]
    u32* pk      = (u32*)d_out;                           // [E] scratch

    const int nb_n  = (N_NODES + 255) / 256;
    const int nb_g8 = (N_NODES * 8 + 255) / 256;          // 3125

    // k1 first: independent of the build; its block 0 zeros bcnt/dcnt.
    k1_lin48<<<nb_n, 256, 0, stream>>>(x, W1_rel, b1, W1_root, Ya, R, bcnt, dcnt);

    // ---- Build: bucket counting sort -> per-node CSR + degree-sorted perm ----
    k_bhist<<<NB_H, 256, 0, stream>>>(dst, bcnt);
    k_bscan<<<1, 1024, 0, stream>>>(bcnt, base, cursor);
    k_partition<<<NB_P, 1024, 0, stream>>>(src, dst, cursor, pk);
    k_bucket_csr<<<NBKT, 1024, 0, stream>>>(base, pk, off_end, csr, dcnt);
    k_degscan<<<1, DBINS, 0, stream>>>(dcnt, dcur);
    k_permfill<<<nb_n, 256, 0, stream>>>(off_end, dcur, perm);

    // ---- Layers (fused gather+transform, 8 lanes/node, degree-sorted) ----
    kA_gather_lin16<<<nb_g8, 256, 0, stream>>>(off_end, csr, perm, Ya, R,
                                               W1b_rel, b1b, W1b_root, Yb);
    kB_gather_tanh<<<nb_g8, 256, 0, stream>>>(off_end, csr, perm, Yb, R, Ya);
    kC_gather_out<<<nb_g8, 256, 0, stream>>>(off_end, csr, perm, Ya,
                                             W2_rel, b2, W2_root, out);
}

// Round 13
// 199.230 us; speedup vs baseline: 3.7227x; 3.7227x over previous
//
#include <hip/hip_runtime.h>
#include <hip/hip_bf16.h>
#include <cmath>

#define N_NODES 100000
#define N_EDGES 1600000
#define IN_F 48
#define HID_F 16
#define OUT_F 60

#define BKT 256                                  // nodes per bucket
#define NBKT ((N_NODES + BKT - 1) / BKT)         // 391
#define EPB 8192                                 // edges per partition block
#define NB_P ((N_EDGES + EPB - 1) / EPB)         // 196
#define EPB_H 2048                               // edges per hist block
#define NB_H ((N_EDGES + EPB_H - 1) / EPB_H)     // 782
#define DBINS 64                                 // degree bins for perm sort
#define PTOT (DBINS * NBKT)                      // 25024
#define PCH ((PTOT + 1023) / 1024)               // 25

typedef __hip_bfloat16 bf16;
typedef float f32x4 __attribute__((ext_vector_type(4)));
typedef unsigned int u32;

__device__ __forceinline__ float bf2f(u32 u)
{
    return __uint_as_float(u << 16);
}
__device__ __forceinline__ u32 pack_bf2(float lo, float hi)
{
    u32 l = __bfloat16_as_ushort(__float2bfloat16(lo));
    u32 h = __bfloat16_as_ushort(__float2bfloat16(hi));
    return l | (h << 16);
}

// ---------------- Build: two-level counting sort -> per-node CSR --------------
__global__ __launch_bounds__(256) void k_bhist(
    const int* __restrict__ dst, int* __restrict__ bcnt)
{
    __shared__ int h[NBKT];
    for (int i = threadIdx.x; i < NBKT; i += 256) h[i] = 0;
    __syncthreads();
    int base = blockIdx.x * EPB_H;
    #pragma unroll
    for (int i = 0; i < EPB_H / 256; ++i) {
        int e = base + i * 256 + threadIdx.x;
        if (e < N_EDGES) atomicAdd(&h[dst[e] >> 8], 1);
    }
    __syncthreads();
    for (int i = threadIdx.x; i < NBKT; i += 256)
        if (h[i]) atomicAdd(&bcnt[i], h[i]);
}

__global__ __launch_bounds__(1024) void k_bscan(
    const int* __restrict__ bcnt, int* __restrict__ base, int* __restrict__ cursor)
{
    __shared__ int tmp[1024];
    int v = (threadIdx.x < NBKT) ? bcnt[threadIdx.x] : 0;
    tmp[threadIdx.x] = v;
    __syncthreads();
    #pragma unroll
    for (int ofs = 1; ofs < 1024; ofs <<= 1) {
        int a = (threadIdx.x >= ofs) ? tmp[threadIdx.x - ofs] : 0;
        __syncthreads();
        tmp[threadIdx.x] += a;
        __syncthreads();
    }
    if (threadIdx.x < NBKT) {
        int ex = tmp[threadIdx.x] - v;
        base[threadIdx.x] = ex;
        cursor[threadIdx.x] = ex;
    }
    if (threadIdx.x == 0) base[NBKT] = N_EDGES;
}

// Partition edges into dst-buckets; packed word = (src << 8) | (dst & 255).
__global__ __launch_bounds__(1024) void k_partition(
    const int* __restrict__ src, const int* __restrict__ dst,
    int* __restrict__ cursor, u32* __restrict__ pk)
{
    __shared__ int cnt[NBKT];
    __shared__ int bb[NBKT];
    for (int i = threadIdx.x; i < NBKT; i += 1024) cnt[i] = 0;
    __syncthreads();
    int e0 = blockIdx.x * EPB;
    int dloc[EPB / 1024];
    #pragma unroll
    for (int i = 0; i < EPB / 1024; ++i) {
        int e = e0 + i * 1024 + threadIdx.x;
        dloc[i] = (e < N_EDGES) ? dst[e] : -1;
        if (dloc[i] >= 0) atomicAdd(&cnt[dloc[i] >> 8], 1);
    }
    __syncthreads();
    for (int i = threadIdx.x; i < NBKT; i += 1024) {
        int c = cnt[i];
        bb[i] = c ? atomicAdd(&cursor[i], c) : 0;
        cnt[i] = 0;
    }
    __syncthreads();
    #pragma unroll
    for (int i = 0; i < EPB / 1024; ++i) {
        int e = e0 + i * 1024 + threadIdx.x;
        int d = dloc[i];
        if (d >= 0) {
            int b = d >> 8;
            int r = atomicAdd(&cnt[b], 1);
            pk[bb[b] + r] = ((u32)src[e] << 8) | (u32)(d & 255);
        }
    }
}

// One block per 256-node bucket (16 waves): per-node CSR in a 16KB hot window.
// Degree histogram goes to pcnt[bin][block] via PLAIN stores (no global atomics).
__global__ __launch_bounds__(1024) void k_bucket_csr(
    const int* __restrict__ base, const u32* __restrict__ pk,
    int* __restrict__ off_end, int* __restrict__ csr, int* __restrict__ pcnt)
{
    __shared__ int hist[BKT];
    __shared__ int tmp[BKT];
    __shared__ int cur[BKT];
    __shared__ int lhist[DBINS];
    int b = blockIdx.x;
    int e0 = base[b], e1 = base[b + 1];
    if (threadIdx.x < BKT) hist[threadIdx.x] = 0;
    if (threadIdx.x < DBINS) lhist[threadIdx.x] = 0;
    __syncthreads();
    for (int e = e0 + threadIdx.x; e < e1; e += 1024)
        atomicAdd(&hist[pk[e] & 255u], 1);
    __syncthreads();
    int v = 0;
    if (threadIdx.x < BKT) { v = hist[threadIdx.x]; tmp[threadIdx.x] = v; }
    __syncthreads();
    #pragma unroll
    for (int ofs = 1; ofs < BKT; ofs <<= 1) {
        int a = (threadIdx.x < BKT && threadIdx.x >= ofs) ? tmp[threadIdx.x - ofs] : 0;
        __syncthreads();
        if (threadIdx.x < BKT) tmp[threadIdx.x] += a;
        __syncthreads();
    }
    if (threadIdx.x < BKT) {
        int incl = tmp[threadIdx.x];
        cur[threadIdx.x] = e0 + incl - v;
        int n = b * BKT + threadIdx.x;
        if (n < N_NODES) {
            off_end[n] = e0 + incl;
            atomicAdd(&lhist[v < DBINS - 1 ? v : DBINS - 1], 1);  // LDS atomic
        }
    }
    __syncthreads();
    if (threadIdx.x < DBINS)
        pcnt[threadIdx.x * NBKT + b] = lhist[threadIdx.x];        // plain store
    for (int e = e0 + threadIdx.x; e < e1; e += 1024) {
        u32 p = pk[e];
        int pos = atomicAdd(&cur[p & 255u], 1);
        csr[pos] = (int)(p >> 8);
    }
}

// In-place exclusive scan of pcnt[DBINS*NBKT]; single block, thread-sequential
// segments + one LDS scan. No atomics.
__global__ __launch_bounds__(1024) void k_pscan(int* __restrict__ pcnt)
{
    __shared__ int part[1024];
    int t = threadIdx.x;
    int s = t * PCH;
    int e = s + PCH < PTOT ? s + PCH : PTOT;
    int sum = 0;
    for (int i = s; i < e; ++i) sum += pcnt[i];
    part[t] = sum;
    __syncthreads();
    #pragma unroll
    for (int ofs = 1; ofs < 1024; ofs <<= 1) {
        int a = (t >= ofs) ? part[t - ofs] : 0;
        __syncthreads();
        part[t] += a;
        __syncthreads();
    }
    int run = part[t] - sum;                 // exclusive base for this segment
    for (int i = s; i < e; ++i) {
        int v = pcnt[i];
        pcnt[i] = run;
        run += v;
    }
}

// Fill perm (ascending degree): LDS cursors seeded from pcnt; LDS atomics only.
// Intra-bin order is arbitrary — each node's math is self-contained, so the
// output is identical regardless of placement order.
__global__ __launch_bounds__(256) void k_permfill(
    const int* __restrict__ off_end, const int* __restrict__ pcnt,
    int* __restrict__ perm)
{
    __shared__ int lcur[DBINS];
    int b = blockIdx.x;
    if (threadIdx.x < DBINS) lcur[threadIdx.x] = pcnt[threadIdx.x * NBKT + b];
    __syncthreads();
    int n = b * 256 + threadIdx.x;
    if (n >= N_NODES) return;
    int e0 = (n == 0) ? 0 : off_end[n - 1];
    int d = off_end[n] - e0;
    int bin = d < DBINS - 1 ? d : DBINS - 1;
    int pos = atomicAdd(&lcur[bin], 1);      // LDS atomic
    perm[pos] = n;
}

// Gather body: 8 lanes per node; lane = feature PAIR (u32 = 2 bf16).
__device__ __forceinline__ float2 gather2(
    const int* __restrict__ off_end, const int* __restrict__ csr_src,
    const u32* __restrict__ Yu, int n, int lane)
{
    int e0 = (n == 0) ? 0 : off_end[n - 1];
    int e1 = off_end[n];
    float x0 = 0.f, y0 = 0.f, x1 = 0.f, y1 = 0.f;
    float x2 = 0.f, y2 = 0.f, x3 = 0.f, y3 = 0.f;
    int e = e0;
    for (; e + 3 < e1; e += 4) {
        int s0 = csr_src[e];
        int s1 = csr_src[e + 1];
        int s2 = csr_src[e + 2];
        int s3 = csr_src[e + 3];
        u32 u0 = Yu[(size_t)s0 * 8 + lane];
        u32 u1 = Yu[(size_t)s1 * 8 + lane];
        u32 u2 = Yu[(size_t)s2 * 8 + lane];
        u32 u3 = Yu[(size_t)s3 * 8 + lane];
        x0 += bf2f(u0 & 0xffffu); y0 += bf2f(u0 >> 16);
        x1 += bf2f(u1 & 0xffffu); y1 += bf2f(u1 >> 16);
        x2 += bf2f(u2 & 0xffffu); y2 += bf2f(u2 >> 16);
        x3 += bf2f(u3 & 0xffffu); y3 += bf2f(u3 >> 16);
    }
    for (; e < e1; ++e) {
        u32 u = Yu[(size_t)csr_src[e] * 8 + lane];
        x0 += bf2f(u & 0xffffu); y0 += bf2f(u >> 16);
    }
    return make_float2((x0 + x1) + (x2 + x3), (y0 + y1) + (y2 + y3));
}

// ------- Layer-1: Ya = bf16(x@W1_rel), R = x@W1_root + b1; block 0 zeros bcnt -
__global__ __launch_bounds__(256) void k1_lin48(
    const float* __restrict__ x, const float* __restrict__ Wrel,
    const float* __restrict__ b, const float* __restrict__ Wroot,
    bf16* __restrict__ Ya, float* __restrict__ R, int* __restrict__ bcnt)
{
    if (blockIdx.x == 0) {
        for (int i = threadIdx.x; i < NBKT; i += 256) bcnt[i] = 0;
    }

    __shared__ float sWrel[IN_F * HID_F];
    __shared__ float sWroot[IN_F * HID_F];
    __shared__ float sb[HID_F];
    for (int i = threadIdx.x; i < IN_F * HID_F; i += 256) {
        sWrel[i]  = Wrel[i];
        sWroot[i] = Wroot[i];
    }
    if (threadIdx.x < HID_F) sb[threadIdx.x] = b[threadIdx.x];
    __syncthreads();

    int n = blockIdx.x * 256 + threadIdx.x;
    if (n >= N_NODES) return;

    float xv[IN_F];
    const f32x4* xr = reinterpret_cast<const f32x4*>(x + (size_t)n * IN_F);
    #pragma unroll
    for (int i = 0; i < IN_F / 4; ++i) {
        f32x4 t = __builtin_nontemporal_load(xr + i);   // x read exactly once
        xv[4*i+0] = t.x; xv[4*i+1] = t.y; xv[4*i+2] = t.z; xv[4*i+3] = t.w;
    }

    float accR[HID_F], accT[HID_F];
    #pragma unroll
    for (int f = 0; f < HID_F; ++f) { accR[f] = 0.0f; accT[f] = sb[f]; }

    #pragma unroll 6
    for (int k = 0; k < IN_F; ++k) {
        float xk = xv[k];
        #pragma unroll
        for (int f = 0; f < HID_F; ++f) {
            accR[f] = fmaf(xk, sWrel[k*HID_F + f], accR[f]);
            accT[f] = fmaf(xk, sWroot[k*HID_F + f], accT[f]);
        }
    }

    union { bf16 h[HID_F]; uint4 q[2]; } yo;
    #pragma unroll
    for (int f = 0; f < HID_F; ++f) yo.h[f] = __float2bfloat16(accR[f]);
    uint4* yq = reinterpret_cast<uint4*>(Ya + (size_t)n * HID_F);
    yq[0] = yo.q[0]; yq[1] = yo.q[1];

    float4* rr = reinterpret_cast<float4*>(R + (size_t)n * HID_F);
    #pragma unroll
    for (int q = 0; q < HID_F / 4; ++q)
        rr[q] = make_float4(accT[4*q], accT[4*q+1], accT[4*q+2], accT[4*q+3]);
}

// -------- kA: gather(Ya) + h=tanh(R+agg); Yb=bf16(h@Wrel); R=h@Wroot+b --------
// 8 lanes/node via perm (degree-sorted schedule: uniform wave workloads).
__global__ __launch_bounds__(256) void kA_gather_lin16(
    const int* __restrict__ off_end, const int* __restrict__ csr_src,
    const int* __restrict__ perm,
    const bf16* __restrict__ Ya, float* __restrict__ R,
    const float* __restrict__ Wrel, const float* __restrict__ bb,
    const float* __restrict__ Wroot, bf16* __restrict__ Yb)
{
    __shared__ float2 sWrel2[HID_F * 8];     // [k][pair l] = (W[k][2l], W[k][2l+1])
    __shared__ float2 sWroot2[HID_F * 8];
    __shared__ float2 sb2[8];
    if (threadIdx.x < HID_F * 8) {
        sWrel2[threadIdx.x]  = reinterpret_cast<const float2*>(Wrel)[threadIdx.x];
        sWroot2[threadIdx.x] = reinterpret_cast<const float2*>(Wroot)[threadIdx.x];
    }
    if (threadIdx.x < 8) sb2[threadIdx.x] = reinterpret_cast<const float2*>(bb)[threadIdx.x];
    __syncthreads();

    int t = blockIdx.x * 256 + threadIdx.x;
    int g = t >> 3;
    int lane = t & 7;
    if (g >= N_NODES) return;
    int n = perm[g];

    float2 agg = gather2(off_end, csr_src, (const u32*)Ya, n, lane);
    float2 r = reinterpret_cast<const float2*>(R)[(size_t)n * 8 + lane];
    float hx_own = tanhf(r.x + agg.x);
    float hy_own = tanhf(r.y + agg.y);

    int base = threadIdx.x & 56;   // 8-lane group base within the wave
    float2 accR = make_float2(0.f, 0.f);
    float2 accT = sb2[lane];
    #pragma unroll
    for (int kk = 0; kk < 8; ++kk) {
        float hx = __shfl(hx_own, base | kk);   // feature k0 = 2*kk
        float hy = __shfl(hy_own, base | kk);   // feature k1 = 2*kk+1
        float2 w0r = sWrel2[(2*kk)   * 8 + lane];
        float2 w1r = sWrel2[(2*kk+1) * 8 + lane];
        float2 w0t = sWroot2[(2*kk)   * 8 + lane];
        float2 w1t = sWroot2[(2*kk+1) * 8 + lane];
        accR.x = fmaf(hx, w0r.x, accR.x); accR.y = fmaf(hx, w0r.y, accR.y);
        accR.x = fmaf(hy, w1r.x, accR.x); accR.y = fmaf(hy, w1r.y, accR.y);
        accT.x = fmaf(hx, w0t.x, accT.x); accT.y = fmaf(hx, w0t.y, accT.y);
        accT.x = fmaf(hy, w1t.x, accT.x); accT.y = fmaf(hy, w1t.y, accT.y);
    }

    ((u32*)Yb)[(size_t)n * 8 + lane] = pack_bf2(accR.x, accR.y);
    reinterpret_cast<float2*>(R)[(size_t)n * 8 + lane] = accT;
}

// -------- kB: h2 = tanh(R + gather(Yb)); Ya = bf16(h2) ------------------------
__global__ __launch_bounds__(256) void kB_gather_tanh(
    const int* __restrict__ off_end, const int* __restrict__ csr_src,
    const int* __restrict__ perm,
    const bf16* __restrict__ Yb, const float* __restrict__ R,
    bf16* __restrict__ Ya)
{
    int t = blockIdx.x * 256 + threadIdx.x;
    int g = t >> 3;
    int lane = t & 7;
    if (g >= N_NODES) return;
    int n = perm[g];

    float2 agg = gather2(off_end, csr_src, (const u32*)Yb, n, lane);
    float2 r = reinterpret_cast<const float2*>(R)[(size_t)n * 8 + lane];
    ((u32*)Ya)[(size_t)n * 8 + lane] =
        pack_bf2(tanhf(r.x + agg.x), tanhf(r.y + agg.y));
}

// -------- kC: out = gather(Ya)@W2_rel + b2 + Ya[n]@W2_root --------------------
__global__ __launch_bounds__(256) void kC_gather_out(
    const int* __restrict__ off_end, const int* __restrict__ csr_src,
    const int* __restrict__ perm,
    const bf16* __restrict__ Ya,
    const float* __restrict__ Wrel, const float* __restrict__ b2,
    const float* __restrict__ Wroot, float* __restrict__ out)
{
    __shared__ float sWrel[HID_F * OUT_F];
    __shared__ float sWroot[HID_F * OUT_F];
    __shared__ float sb[OUT_F];
    for (int i = threadIdx.x; i < HID_F * OUT_F; i += 256) {
        sWrel[i]  = Wrel[i];
        sWroot[i] = Wroot[i];
    }
    if (threadIdx.x < OUT_F) sb[threadIdx.x] = b2[threadIdx.x];
    __syncthreads();

    int t = blockIdx.x * 256 + threadIdx.x;
    int g = t >> 3;
    int lane = t & 7;
    if (g >= N_NODES) return;
    int n = perm[g];

    float2 agg = gather2(off_end, csr_src, (const u32*)Ya, n, lane);
    u32 hown = ((const u32*)Ya)[(size_t)n * 8 + lane];
    float hx_own = bf2f(hown & 0xffffu);
    float hy_own = bf2f(hown >> 16);

    int base = threadIdx.x & 56;
    float acc[8];
    #pragma unroll
    for (int q = 0; q < 8; ++q) {
        int j = q * 8 + lane;
        acc[q] = (j < OUT_F) ? sb[j] : 0.f;
    }
    #pragma unroll
    for (int kk = 0; kk < 8; ++kk) {
        float ax = __shfl(agg.x, base | kk);   // agg feature 2*kk
        float ay = __shfl(agg.y, base | kk);   // agg feature 2*kk+1
        float hx = __shfl(hx_own, base | kk);
        float hy = __shfl(hy_own, base | kk);
        const float* wr0 = sWrel  + (2*kk)   * OUT_F;
        const float* wr1 = sWrel  + (2*kk+1) * OUT_F;
        const float* wt0 = sWroot + (2*kk)   * OUT_F;
        const float* wt1 = sWroot + (2*kk+1) * OUT_F;
        #pragma unroll
        for (int q = 0; q < 8; ++q) {
            int j = q * 8 + lane;
            if (j < OUT_F) {
                acc[q] = fmaf(ax, wr0[j], acc[q]);
                acc[q] = fmaf(ay, wr1[j], acc[q]);
                acc[q] = fmaf(hx, wt0[j], acc[q]);
                acc[q] = fmaf(hy, wt1[j], acc[q]);
            }
        }
    }
    // nt store: out is a pure write-once stream; keep Ya resident in L2.
    float* orow = out + (size_t)n * OUT_F;
    #pragma unroll
    for (int q = 0; q < 8; ++q) {
        int j = q * 8 + lane;
        if (j < OUT_F) __builtin_nontemporal_store(acc[q], orow + j);
    }
}

extern "C" void kernel_launch(void* const* d_in, const int* in_sizes, int n_in,
                              void* d_out, int out_size, void* d_ws, size_t ws_size,
                              hipStream_t stream)
{
    const float* x        = (const float*)d_in[0];
    const int*   ei       = (const int*)d_in[1];
    const float* W1_rel   = (const float*)d_in[2];
    const float* b1       = (const float*)d_in[3];
    const float* W1_root  = (const float*)d_in[4];
    const float* W1b_rel  = (const float*)d_in[5];
    const float* b1b      = (const float*)d_in[6];
    const float* W1b_root = (const float*)d_in[7];
    const float* W2_rel   = (const float*)d_in[8];
    const float* b2       = (const float*)d_in[9];
    const float* W2_root  = (const float*)d_in[10];
    float* out = (float*)d_out;

    const int* src = ei;            // edge_index[0]
    const int* dst = ei + N_EDGES;  // edge_index[1]

    // Workspace (~20.1 MB). pk aliases d_out (consumed in build, before kC).
    bf16* Ya     = (bf16*)d_ws;                           // [N,16] bf16
    bf16* Yb     = Ya + (size_t)N_NODES * HID_F;          // [N,16] bf16
    float* R     = (float*)(Yb + (size_t)N_NODES * HID_F);// [N,16] f32
    int* csr     = (int*)(R + (size_t)N_NODES * HID_F);   // [E]
    int* off_end = csr + N_EDGES;                         // [N]
    int* perm    = off_end + N_NODES;                     // [N]
    int* bcnt    = perm + N_NODES;                        // [NBKT]
    int* base    = bcnt + NBKT;                           // [NBKT+1]
    int* cursor  = base + NBKT + 1;                       // [NBKT]
    int* pcnt    = cursor + NBKT;                         // [DBINS*NBKT]
    u32* pk      = (u32*)d_out;                           // [E] scratch

    const int nb_n  = (N_NODES + 255) / 256;
    const int nb_g8 = (N_NODES * 8 + 255) / 256;          // 3125

    // k1 first: independent of the build; its block 0 zeros bcnt.
    k1_lin48<<<nb_n, 256, 0, stream>>>(x, W1_rel, b1, W1_root, Ya, R, bcnt);

    // ---- Build: bucket counting sort -> per-node CSR + degree-sorted perm ----
    k_bhist<<<NB_H, 256, 0, stream>>>(dst, bcnt);
    k_bscan<<<1, 1024, 0, stream>>>(bcnt, base, cursor);
    k_partition<<<NB_P, 1024, 0, stream>>>(src, dst, cursor, pk);
    k_bucket_csr<<<NBKT, 1024, 0, stream>>>(base, pk, off_end, csr, pcnt);
    k_pscan<<<1, 1024, 0, stream>>>(pcnt);
    k_permfill<<<nb_n, 256, 0, stream>>>(off_end, pcnt, perm);

    // ---- Layers (fused gather+transform, 8 lanes/node, degree-sorted) ----
    kA_gather_lin16<<<nb_g8, 256, 0, stream>>>(off_end, csr, perm, Ya, R,
                                               W1b_rel, b1b, W1b_root, Yb);
    kB_gather_tanh<<<nb_g8, 256, 0, stream>>>(off_end, csr, perm, Yb, R, Ya);
    kC_gather_out<<<nb_g8, 256, 0, stream>>>(off_end, csr, perm, Ya,
                                             W2_rel, b2, W2_root, out);
}

// Round 14
// 153.488 us; speedup vs baseline: 4.8321x; 1.2980x over previous
//
#include <hip/hip_runtime.h>
#include <hip/hip_bf16.h>
#include <cmath>

#define N_NODES 100000
#define N_EDGES 1600000
#define IN_F 48
#define HID_F 16
#define OUT_F 60

#define BKT 256                                  // nodes per bucket
#define NBKT ((N_NODES + BKT - 1) / BKT)         // 391
#define EPB 8192                                 // edges per partition block
#define NB_P ((N_EDGES + EPB - 1) / EPB)         // 196
#define EPB_H 2048                               // edges per hist block
#define NB_H ((N_EDGES + EPB_H - 1) / EPB_H)     // 782

typedef __hip_bfloat16 bf16;
typedef float f32x4 __attribute__((ext_vector_type(4)));
typedef unsigned int u32;

__device__ __forceinline__ float bf2f(u32 u)
{
    return __uint_as_float(u << 16);
}
__device__ __forceinline__ u32 pack_bf2(float lo, float hi)
{
    u32 l = __bfloat16_as_ushort(__float2bfloat16(lo));
    u32 h = __bfloat16_as_ushort(__float2bfloat16(hi));
    return l | (h << 16);
}

// ---------------- Build: two-level counting sort -> per-node CSR --------------
__global__ __launch_bounds__(256) void k_bhist(
    const int* __restrict__ dst, int* __restrict__ bcnt)
{
    __shared__ int h[NBKT];
    for (int i = threadIdx.x; i < NBKT; i += 256) h[i] = 0;
    __syncthreads();
    int base = blockIdx.x * EPB_H;
    #pragma unroll
    for (int i = 0; i < EPB_H / 256; ++i) {
        int e = base + i * 256 + threadIdx.x;
        if (e < N_EDGES) atomicAdd(&h[dst[e] >> 8], 1);
    }
    __syncthreads();
    for (int i = threadIdx.x; i < NBKT; i += 256)
        if (h[i]) atomicAdd(&bcnt[i], h[i]);
}

__global__ __launch_bounds__(1024) void k_bscan(
    const int* __restrict__ bcnt, int* __restrict__ base, int* __restrict__ cursor)
{
    __shared__ int tmp[1024];
    int v = (threadIdx.x < NBKT) ? bcnt[threadIdx.x] : 0;
    tmp[threadIdx.x] = v;
    __syncthreads();
    #pragma unroll
    for (int ofs = 1; ofs < 1024; ofs <<= 1) {
        int a = (threadIdx.x >= ofs) ? tmp[threadIdx.x - ofs] : 0;
        __syncthreads();
        tmp[threadIdx.x] += a;
        __syncthreads();
    }
    if (threadIdx.x < NBKT) {
        int ex = tmp[threadIdx.x] - v;
        base[threadIdx.x] = ex;
        cursor[threadIdx.x] = ex;
    }
    if (threadIdx.x == 0) base[NBKT] = N_EDGES;
}

// Partition edges into dst-buckets; packed word = (src << 8) | (dst & 255).
__global__ __launch_bounds__(1024) void k_partition(
    const int* __restrict__ src, const int* __restrict__ dst,
    int* __restrict__ cursor, u32* __restrict__ pk)
{
    __shared__ int cnt[NBKT];
    __shared__ int bb[NBKT];
    for (int i = threadIdx.x; i < NBKT; i += 1024) cnt[i] = 0;
    __syncthreads();
    int e0 = blockIdx.x * EPB;
    int dloc[EPB / 1024];
    #pragma unroll
    for (int i = 0; i < EPB / 1024; ++i) {
        int e = e0 + i * 1024 + threadIdx.x;
        dloc[i] = (e < N_EDGES) ? dst[e] : -1;
        if (dloc[i] >= 0) atomicAdd(&cnt[dloc[i] >> 8], 1);
    }
    __syncthreads();
    for (int i = threadIdx.x; i < NBKT; i += 1024) {
        int c = cnt[i];
        bb[i] = c ? atomicAdd(&cursor[i], c) : 0;
        cnt[i] = 0;
    }
    __syncthreads();
    #pragma unroll
    for (int i = 0; i < EPB / 1024; ++i) {
        int e = e0 + i * 1024 + threadIdx.x;
        int d = dloc[i];
        if (d >= 0) {
            int b = d >> 8;
            int r = atomicAdd(&cnt[b], 1);
            pk[bb[b] + r] = ((u32)src[e] << 8) | (u32)(d & 255);
        }
    }
}

// One block per 256-node bucket (16 waves): per-node CSR in a 16KB hot window.
__global__ __launch_bounds__(1024) void k_bucket_csr(
    const int* __restrict__ base, const u32* __restrict__ pk,
    int* __restrict__ off_end, int* __restrict__ csr)
{
    __shared__ int hist[BKT];
    __shared__ int tmp[BKT];
    __shared__ int cur[BKT];
    int b = blockIdx.x;
    int e0 = base[b], e1 = base[b + 1];
    if (threadIdx.x < BKT) hist[threadIdx.x] = 0;
    __syncthreads();
    for (int e = e0 + threadIdx.x; e < e1; e += 1024)
        atomicAdd(&hist[pk[e] & 255u], 1);
    __syncthreads();
    int v = 0;
    if (threadIdx.x < BKT) { v = hist[threadIdx.x]; tmp[threadIdx.x] = v; }
    __syncthreads();
    #pragma unroll
    for (int ofs = 1; ofs < BKT; ofs <<= 1) {
        int a = (threadIdx.x < BKT && threadIdx.x >= ofs) ? tmp[threadIdx.x - ofs] : 0;
        __syncthreads();
        if (threadIdx.x < BKT) tmp[threadIdx.x] += a;
        __syncthreads();
    }
    if (threadIdx.x < BKT) {
        int incl = tmp[threadIdx.x];
        cur[threadIdx.x] = e0 + incl - v;
        int n = b * BKT + threadIdx.x;
        if (n < N_NODES) off_end[n] = e0 + incl;
    }
    __syncthreads();
    for (int e = e0 + threadIdx.x; e < e1; e += 1024) {
        u32 p = pk[e];
        int pos = atomicAdd(&cur[p & 255u], 1);
        csr[pos] = (int)(p >> 8);
    }
}

// Gather body: 4 lanes per node; lane = feature QUAD (uint2 = 4 bf16).
// 16 nodes per wave -> 2x outstanding row-misses vs the 8-lane variant.
__device__ __forceinline__ float4 gather4(
    const int* __restrict__ off_end, const int* __restrict__ csr_src,
    const uint2* __restrict__ Yu, int n, int lane)
{
    int e0 = (n == 0) ? 0 : off_end[n - 1];
    int e1 = off_end[n];
    float x0 = 0.f, y0 = 0.f, z0 = 0.f, w0 = 0.f;
    float x1 = 0.f, y1 = 0.f, z1 = 0.f, w1 = 0.f;
    float x2 = 0.f, y2 = 0.f, z2 = 0.f, w2 = 0.f;
    float x3 = 0.f, y3 = 0.f, z3 = 0.f, w3 = 0.f;
    int e = e0;
    for (; e + 3 < e1; e += 4) {
        int s0 = csr_src[e];
        int s1 = csr_src[e + 1];
        int s2 = csr_src[e + 2];
        int s3 = csr_src[e + 3];
        uint2 u0 = Yu[(size_t)s0 * 4 + lane];
        uint2 u1 = Yu[(size_t)s1 * 4 + lane];
        uint2 u2 = Yu[(size_t)s2 * 4 + lane];
        uint2 u3 = Yu[(size_t)s3 * 4 + lane];
        x0 += bf2f(u0.x & 0xffffu); y0 += bf2f(u0.x >> 16);
        z0 += bf2f(u0.y & 0xffffu); w0 += bf2f(u0.y >> 16);
        x1 += bf2f(u1.x & 0xffffu); y1 += bf2f(u1.x >> 16);
        z1 += bf2f(u1.y & 0xffffu); w1 += bf2f(u1.y >> 16);
        x2 += bf2f(u2.x & 0xffffu); y2 += bf2f(u2.x >> 16);
        z2 += bf2f(u2.y & 0xffffu); w2 += bf2f(u2.y >> 16);
        x3 += bf2f(u3.x & 0xffffu); y3 += bf2f(u3.x >> 16);
        z3 += bf2f(u3.y & 0xffffu); w3 += bf2f(u3.y >> 16);
    }
    for (; e < e1; ++e) {
        uint2 u = Yu[(size_t)csr_src[e] * 4 + lane];
        x0 += bf2f(u.x & 0xffffu); y0 += bf2f(u.x >> 16);
        z0 += bf2f(u.y & 0xffffu); w0 += bf2f(u.y >> 16);
    }
    return make_float4((x0 + x1) + (x2 + x3), (y0 + y1) + (y2 + y3),
                       (z0 + z1) + (z2 + z3), (w0 + w1) + (w2 + w3));
}

// ------- Layer-1: Ya = bf16(x@W1_rel), R = x@W1_root + b1; block 0 zeros bcnt -
__global__ __launch_bounds__(256) void k1_lin48(
    const float* __restrict__ x, const float* __restrict__ Wrel,
    const float* __restrict__ b, const float* __restrict__ Wroot,
    bf16* __restrict__ Ya, float* __restrict__ R, int* __restrict__ bcnt)
{
    if (blockIdx.x == 0) {
        for (int i = threadIdx.x; i < NBKT; i += 256) bcnt[i] = 0;
    }

    __shared__ float sWrel[IN_F * HID_F];
    __shared__ float sWroot[IN_F * HID_F];
    __shared__ float sb[HID_F];
    for (int i = threadIdx.x; i < IN_F * HID_F; i += 256) {
        sWrel[i]  = Wrel[i];
        sWroot[i] = Wroot[i];
    }
    if (threadIdx.x < HID_F) sb[threadIdx.x] = b[threadIdx.x];
    __syncthreads();

    int n = blockIdx.x * 256 + threadIdx.x;
    if (n >= N_NODES) return;

    float xv[IN_F];
    const f32x4* xr = reinterpret_cast<const f32x4*>(x + (size_t)n * IN_F);
    #pragma unroll
    for (int i = 0; i < IN_F / 4; ++i) {
        f32x4 t = __builtin_nontemporal_load(xr + i);   // x read exactly once
        xv[4*i+0] = t.x; xv[4*i+1] = t.y; xv[4*i+2] = t.z; xv[4*i+3] = t.w;
    }

    float accR[HID_F], accT[HID_F];
    #pragma unroll
    for (int f = 0; f < HID_F; ++f) { accR[f] = 0.0f; accT[f] = sb[f]; }

    #pragma unroll 6
    for (int k = 0; k < IN_F; ++k) {
        float xk = xv[k];
        #pragma unroll
        for (int f = 0; f < HID_F; ++f) {
            accR[f] = fmaf(xk, sWrel[k*HID_F + f], accR[f]);
            accT[f] = fmaf(xk, sWroot[k*HID_F + f], accT[f]);
        }
    }

    union { bf16 h[HID_F]; uint4 q[2]; } yo;
    #pragma unroll
    for (int f = 0; f < HID_F; ++f) yo.h[f] = __float2bfloat16(accR[f]);
    uint4* yq = reinterpret_cast<uint4*>(Ya + (size_t)n * HID_F);
    yq[0] = yo.q[0]; yq[1] = yo.q[1];

    float4* rr = reinterpret_cast<float4*>(R + (size_t)n * HID_F);
    #pragma unroll
    for (int q = 0; q < HID_F / 4; ++q)
        rr[q] = make_float4(accT[4*q], accT[4*q+1], accT[4*q+2], accT[4*q+3]);
}

// -------- kA: gather(Ya) + h=tanh(R+agg); Yb=bf16(h@Wrel); R=h@Wroot+b --------
// 4 lanes/node; lane owns features [4l, 4l+4).
__global__ __launch_bounds__(256) void kA_gather_lin16(
    const int* __restrict__ off_end, const int* __restrict__ csr_src,
    const bf16* __restrict__ Ya, float* __restrict__ R,
    const float* __restrict__ Wrel, const float* __restrict__ bb,
    const float* __restrict__ Wroot, bf16* __restrict__ Yb)
{
    __shared__ float4 sWrel4[HID_F * 4];     // [k*4 + l] = W[k][4l..4l+3]
    __shared__ float4 sWroot4[HID_F * 4];
    __shared__ float4 sb4[4];
    if (threadIdx.x < HID_F * 4) {
        sWrel4[threadIdx.x]  = reinterpret_cast<const float4*>(Wrel)[threadIdx.x];
        sWroot4[threadIdx.x] = reinterpret_cast<const float4*>(Wroot)[threadIdx.x];
    }
    if (threadIdx.x < 4) sb4[threadIdx.x] = reinterpret_cast<const float4*>(bb)[threadIdx.x];
    __syncthreads();

    int t = blockIdx.x * 256 + threadIdx.x;
    int n = t >> 2;
    int lane = t & 3;
    if (n >= N_NODES) return;

    float4 agg = gather4(off_end, csr_src, (const uint2*)Ya, n, lane);
    float4 r = reinterpret_cast<const float4*>(R)[(size_t)n * 4 + lane];
    float h0 = tanhf(r.x + agg.x);
    float h1 = tanhf(r.y + agg.y);
    float h2 = tanhf(r.z + agg.z);
    float h3 = tanhf(r.w + agg.w);

    int base = threadIdx.x & 60;   // 4-lane group base within the wave
    float4 accR = make_float4(0.f, 0.f, 0.f, 0.f);
    float4 accT = sb4[lane];
    #pragma unroll
    for (int kk = 0; kk < 4; ++kk) {
        float f0 = __shfl(h0, base | kk);   // feature 4*kk+0
        float f1 = __shfl(h1, base | kk);   // feature 4*kk+1
        float f2 = __shfl(h2, base | kk);   // feature 4*kk+2
        float f3 = __shfl(h3, base | kk);   // feature 4*kk+3
        #pragma unroll
        for (int i = 0; i < 4; ++i) {
            float fv = (i == 0) ? f0 : (i == 1) ? f1 : (i == 2) ? f2 : f3;
            float4 wr = sWrel4[(4*kk + i) * 4 + lane];
            float4 wt = sWroot4[(4*kk + i) * 4 + lane];
            accR.x = fmaf(fv, wr.x, accR.x); accR.y = fmaf(fv, wr.y, accR.y);
            accR.z = fmaf(fv, wr.z, accR.z); accR.w = fmaf(fv, wr.w, accR.w);
            accT.x = fmaf(fv, wt.x, accT.x); accT.y = fmaf(fv, wt.y, accT.y);
            accT.z = fmaf(fv, wt.z, accT.z); accT.w = fmaf(fv, wt.w, accT.w);
        }
    }

    uint2 yo;
    yo.x = pack_bf2(accR.x, accR.y);
    yo.y = pack_bf2(accR.z, accR.w);
    ((uint2*)Yb)[(size_t)n * 4 + lane] = yo;
    reinterpret_cast<float4*>(R)[(size_t)n * 4 + lane] = accT;
}

// -------- kB: h2 = tanh(R + gather(Yb)); Ya = bf16(h2) ------------------------
__global__ __launch_bounds__(256) void kB_gather_tanh(
    const int* __restrict__ off_end, const int* __restrict__ csr_src,
    const bf16* __restrict__ Yb, const float* __restrict__ R,
    bf16* __restrict__ Ya)
{
    int t = blockIdx.x * 256 + threadIdx.x;
    int n = t >> 2;
    int lane = t & 3;
    if (n >= N_NODES) return;

    float4 agg = gather4(off_end, csr_src, (const uint2*)Yb, n, lane);
    float4 r = reinterpret_cast<const float4*>(R)[(size_t)n * 4 + lane];
    uint2 yo;
    yo.x = pack_bf2(tanhf(r.x + agg.x), tanhf(r.y + agg.y));
    yo.y = pack_bf2(tanhf(r.z + agg.z), tanhf(r.w + agg.w));
    ((uint2*)Ya)[(size_t)n * 4 + lane] = yo;
}

// -------- kC: out = gather(Ya)@W2_rel + b2 + Ya[n]@W2_root --------------------
// 4 lanes/node; lane computes output features j = q*4+lane, q=0..14 (all <60).
__global__ __launch_bounds__(256) void kC_gather_out(
    const int* __restrict__ off_end, const int* __restrict__ csr_src,
    const bf16* __restrict__ Ya,
    const float* __restrict__ Wrel, const float* __restrict__ b2,
    const float* __restrict__ Wroot, float* __restrict__ out)
{
    __shared__ float sWrel[HID_F * OUT_F];
    __shared__ float sWroot[HID_F * OUT_F];
    __shared__ float sb[OUT_F];
    for (int i = threadIdx.x; i < HID_F * OUT_F; i += 256) {
        sWrel[i]  = Wrel[i];
        sWroot[i] = Wroot[i];
    }
    if (threadIdx.x < OUT_F) sb[threadIdx.x] = b2[threadIdx.x];
    __syncthreads();

    int t = blockIdx.x * 256 + threadIdx.x;
    int n = t >> 2;
    int lane = t & 3;
    if (n >= N_NODES) return;

    float4 agg = gather4(off_end, csr_src, (const uint2*)Ya, n, lane);
    uint2 hown = ((const uint2*)Ya)[(size_t)n * 4 + lane];
    float h0 = bf2f(hown.x & 0xffffu);
    float h1 = bf2f(hown.x >> 16);
    float h2 = bf2f(hown.y & 0xffffu);
    float h3 = bf2f(hown.y >> 16);

    int base = threadIdx.x & 60;
    float acc[15];
    #pragma unroll
    for (int q = 0; q < 15; ++q) acc[q] = sb[q * 4 + lane];

    #pragma unroll
    for (int kk = 0; kk < 4; ++kk) {
        float a0 = __shfl(agg.x, base | kk);
        float a1 = __shfl(agg.y, base | kk);
        float a2 = __shfl(agg.z, base | kk);
        float a3 = __shfl(agg.w, base | kk);
        float g0 = __shfl(h0, base | kk);
        float g1 = __shfl(h1, base | kk);
        float g2 = __shfl(h2, base | kk);
        float g3 = __shfl(h3, base | kk);
        #pragma unroll
        for (int i = 0; i < 4; ++i) {
            float av = (i == 0) ? a0 : (i == 1) ? a1 : (i == 2) ? a2 : a3;
            float gv = (i == 0) ? g0 : (i == 1) ? g1 : (i == 2) ? g2 : g3;
            const float* wr = sWrel  + (4*kk + i) * OUT_F;
            const float* wt = sWroot + (4*kk + i) * OUT_F;
            #pragma unroll
            for (int q = 0; q < 15; ++q) {
                int j = q * 4 + lane;
                acc[q] = fmaf(av, wr[j], acc[q]);
                acc[q] = fmaf(gv, wt[j], acc[q]);
            }
        }
    }
    // nt store: out is a pure write-once stream; keep Ya resident in L2.
    float* orow = out + (size_t)n * OUT_F;
    #pragma unroll
    for (int q = 0; q < 15; ++q)
        __builtin_nontemporal_store(acc[q], orow + q * 4 + lane);
}

extern "C" void kernel_launch(void* const* d_in, const int* in_sizes, int n_in,
                              void* d_out, int out_size, void* d_ws, size_t ws_size,
                              hipStream_t stream)
{
    const float* x        = (const float*)d_in[0];
    const int*   ei       = (const int*)d_in[1];
    const float* W1_rel   = (const float*)d_in[2];
    const float* b1       = (const float*)d_in[3];
    const float* W1_root  = (const float*)d_in[4];
    const float* W1b_rel  = (const float*)d_in[5];
    const float* b1b      = (const float*)d_in[6];
    const float* W1b_root = (const float*)d_in[7];
    const float* W2_rel   = (const float*)d_in[8];
    const float* b2       = (const float*)d_in[9];
    const float* W2_root  = (const float*)d_in[10];
    float* out = (float*)d_out;

    const int* src = ei;            // edge_index[0]
    const int* dst = ei + N_EDGES;  // edge_index[1]

    // Workspace (~19.6 MB). pk aliases d_out (consumed in build, before kC).
    bf16* Ya     = (bf16*)d_ws;                           // [N,16] bf16
    bf16* Yb     = Ya + (size_t)N_NODES * HID_F;          // [N,16] bf16
    float* R     = (float*)(Yb + (size_t)N_NODES * HID_F);// [N,16] f32
    int* csr     = (int*)(R + (size_t)N_NODES * HID_F);   // [E]
    int* off_end = csr + N_EDGES;                         // [N]
    int* bcnt    = off_end + N_NODES;                     // [NBKT]
    int* base    = bcnt + NBKT;                           // [NBKT+1]
    int* cursor  = base + NBKT + 1;                       // [NBKT]
    u32* pk      = (u32*)d_out;                           // [E] scratch

    const int nb_n  = (N_NODES + 255) / 256;
    const int nb_g4 = (N_NODES * 4 + 255) / 256;          // 1563

    // k1 first: independent of the build; its block 0 zeros bcnt.
    k1_lin48<<<nb_n, 256, 0, stream>>>(x, W1_rel, b1, W1_root, Ya, R, bcnt);

    // ---- Build: bucket counting sort -> per-node CSR ----
    k_bhist<<<NB_H, 256, 0, stream>>>(dst, bcnt);
    k_bscan<<<1, 1024, 0, stream>>>(bcnt, base, cursor);
    k_partition<<<NB_P, 1024, 0, stream>>>(src, dst, cursor, pk);
    k_bucket_csr<<<NBKT, 1024, 0, stream>>>(base, pk, off_end, csr);

    // ---- Layers (fused gather+transform, 4 lanes/node) ----
    kA_gather_lin16<<<nb_g4, 256, 0, stream>>>(off_end, csr, Ya, R,
                                               W1b_rel, b1b, W1b_root, Yb);
    kB_gather_tanh<<<nb_g4, 256, 0, stream>>>(off_end, csr, Yb, R, Ya);
    kC_gather_out<<<nb_g4, 256, 0, stream>>>(off_end, csr, Ya,
                                             W2_rel, b2, W2_root, out);
}